// Round 2
// baseline (198.384 us; speedup 1.0000x reference)
//
#include <hip/hip_runtime.h>

// Fused 4x upsample: composite of two polyphase 2x stages (off=1 then off=0).
// out[t] = sum_n g[t-2-4n] x[n] (circular), g = f (*) up2(f), 67 taps.
// Phase structure: s%4==0 -> copy only (g[0]=1); s%4==2 -> 12 taps; odd -> 17.
// Per output col t: r=(t+31)&3, n_max=(t+31)>>2, out = sum_k gPad[r+1+4k]*x[n_max-k].

#define TW 64            // output tile (64x64)
#define PS 33            // input patch (33x33)
#define SIN_STRIDE 48    // LDS pad: stride 48 dwords == 16 mod 32 -> 2-way max (free)

__global__ __launch_bounds__(256) void up4_fused(
    const float* __restrict__ in, const float* __restrict__ kern,
    float* __restrict__ out, int H, int W) {
    __shared__ float sG[80];                 // gPad[u] = g[u-34], zero outside |s|<=33
    __shared__ float sIn[PS][SIN_STRIDE];    // input patch
    __shared__ float sMid[PS][TW];           // horizontally filtered rows

    const int tid = threadIdx.x;
    const int tX = blockIdx.x, tY = blockIdx.y, ch = blockIdx.z;
    const int W4 = 4 * W;

    // ---- composite taps: g[s] = sum_j f[s-2j]*f[j], f[i]=kern[11+i] ----
    if (tid < 80) {
        float acc = 0.f;
        const int s = tid - 34;
        if (tid >= 1 && tid <= 67) {
            #pragma unroll 1
            for (int j = -11; j <= 11; ++j) {
                const int i1 = s - 2 * j;
                if (i1 >= -11 && i1 <= 11)
                    acc += kern[11 + i1] * kern[11 + j];
            }
        }
        sG[tid] = acc;
    }

    // ---- load 33x33 input patch with circular wrap ----
    const float* inC = in + (size_t)ch * H * W;
    const int N0y = 16 * tY - 9, N0x = 16 * tX - 9;
    for (int idx = tid; idx < PS * PS; idx += 256) {
        const int pi = idx / PS, pj = idx - pi * PS;
        int gi = N0y + pi; if (gi < 0) gi += H; else if (gi >= H) gi -= H;
        int gj = N0x + pj; if (gj < 0) gj += W; else if (gj >= W) gj -= W;
        sIn[pi][pj] = inC[(size_t)gi * W + gj];
    }
    __syncthreads();

    // ---- cache taps in registers (shared by both passes) ----
    float tapA[17], tapB[17], tapC[12];
    #pragma unroll
    for (int k = 0; k < 17; ++k) { tapA[k] = sG[1 + 4 * k]; tapB[k] = sG[3 + 4 * k]; }
    #pragma unroll
    for (int k = 0; k < 12; ++k) tapC[k] = sG[12 + 4 * k];

    // ---- horizontal polyphase: 33 rows x 16 col-quads -> sMid[row][64] ----
    // cols 4c+{0,1,2,3}: a0=12-tap(tapC), a1=17-tap(tapA), a2=copy, a3=17-tap(tapB)
    for (int idx = tid; idx < PS * 16; idx += 256) {
        const int c = idx & 15, row = idx >> 4;
        float a0 = 0.f, a1 = 0.f, a2 = 0.f, a3 = 0.f;
        #pragma unroll
        for (int k = 0; k < 17; ++k) {
            const float w = sIn[row][c + 17 - k];   // = x[16tX + c + 8 - k]
            a1 += tapA[k] * w;
            a3 += tapB[k] * w;
            if (k >= 3 && k <= 14) a0 += tapC[k - 3] * w;
            if (k == 8) a2 = w;
        }
        float4 v; v.x = a0; v.y = a1; v.z = a2; v.w = a3;
        *(float4*)&sMid[row][4 * c] = v;
    }
    __syncthreads();

    // ---- vertical polyphase: one task/thread: rowgroup grp(16) x colquad c(16) ----
    {
        const int c = tid & 15, grp = tid >> 4;
        float4 A0, A1, A2, A3;
        A0.x = A0.y = A0.z = A0.w = 0.f;
        A1.x = A1.y = A1.z = A1.w = 0.f;
        A2.x = A2.y = A2.z = A2.w = 0.f;
        A3.x = A3.y = A3.z = A3.w = 0.f;
        #pragma unroll
        for (int k = 0; k < 17; ++k) {
            const float4 R = *(const float4*)&sMid[grp + 17 - k][4 * c];
            A1.x += tapA[k] * R.x; A1.y += tapA[k] * R.y;
            A1.z += tapA[k] * R.z; A1.w += tapA[k] * R.w;
            A3.x += tapB[k] * R.x; A3.y += tapB[k] * R.y;
            A3.z += tapB[k] * R.z; A3.w += tapB[k] * R.w;
            if (k >= 3 && k <= 14) {
                const float t = tapC[k - 3];
                A0.x += t * R.x; A0.y += t * R.y; A0.z += t * R.z; A0.w += t * R.w;
            }
            if (k == 8) A2 = R;   // copy row: g[0]=1 exactly
        }
        float* outC = out + (size_t)ch * (size_t)(4 * H) * W4;
        const size_t base = (size_t)(64 * tY + 4 * grp) * W4 + (64 * tX + 4 * c);
        *(float4*)&outC[base + 0 * W4] = A0;  // dy=4g+0: 12-tap phase
        *(float4*)&outC[base + 1 * W4] = A1;  // dy=4g+1: 17-tap (tapA)
        *(float4*)&outC[base + 2 * W4] = A2;  // dy=4g+2: copy
        *(float4*)&outC[base + 3 * W4] = A3;  // dy=4g+3: 17-tap (tapB)
    }
}

extern "C" void kernel_launch(void* const* d_in, const int* in_sizes, int n_in,
                              void* d_out, int out_size, void* d_ws, size_t ws_size,
                              hipStream_t stream) {
    const float* x    = (const float*)d_in[0];   // (32, 256, 256)
    const float* kern = (const float*)d_in[1];   // 23 taps
    float* out = (float*)d_out;                  // (32, 1024, 1024)

    dim3 blk(256);
    dim3 grid(16, 16, 32);                       // 64x64 output tiles
    up4_fused<<<grid, blk, 0, stream>>>(x, kern, out, 256, 256);
}

// Round 3
// 147.218 us; speedup vs baseline: 1.3475x; 1.3475x over previous
//
#include <hip/hip_runtime.h>

// Fused 4x upsample (two polyphase 2x stages composed): out[t] = sum_n g[t-2-4n] x[n],
// g = f (*) up2(f), 67 taps, circular. g is symmetric: tapB[k]=tapA[16-k], tapC[m]=tapC[11-m].
// Phases of out col/row t mod 4: 0 -> 12-tap (tapC), 1 -> 17-tap (tapA), 2 -> copy, 3 -> tapA reversed.

#define SINS 50      // sIn row stride (49 used +1)
#define SMS 132      // sMid row stride (128 + 4 pad)

__global__ void compute_g(const float* __restrict__ kern, float* __restrict__ gbuf) {
    const int u = threadIdx.x;          // 0..79, gbuf[u] = g[u-34]
    const int s = u - 34;
    int jlo = (s - 11 + 1) >> 1;        // ceil((s-11)/2)
    int jhi = (s + 11) >> 1;            // floor((s+11)/2)
    if (jlo < -11) jlo = -11;
    if (jhi > 11) jhi = 11;
    float acc = 0.f;
    for (int j = jlo; j <= jhi; ++j)
        acc += kern[11 + s - 2 * j] * kern[11 + j];
    gbuf[u] = acc;
}

__device__ inline void fma4(float4& a, float t, const float4& r) {
    a.x += t * r.x; a.y += t * r.y; a.z += t * r.z; a.w += t * r.w;
}

__global__ __launch_bounds__(256, 4) void up4_fused(
    const float* __restrict__ in, const float* __restrict__ gbuf,
    float* __restrict__ out) {
    __shared__ float sG[80];
    __shared__ __attribute__((aligned(16))) float sMid[49][SMS];
    __shared__ float sIn[49][SINS];

    const int tid = threadIdx.x;
    const int tX = blockIdx.x, tY = blockIdx.y, ch = blockIdx.z;
    const int W4 = 1024;

    if (tid < 80) sG[tid] = gbuf[tid];

    // ---- load 48x48 input patch (indices [1..48]), circular wrap via &255 ----
    const float* inC = in + (size_t)ch * 256 * 256;
    const int N0y = 32 * tY - 9, N0x = 32 * tX - 9;
#pragma unroll
    for (int it = 0; it < 9; ++it) {
        const int idx = tid + it * 256;             // 0..2303
        const int pi = 1 + idx / 48, pj = 1 + idx % 48;
        const int gi = (N0y + pi + 256) & 255;
        const int gj = (N0x + pj + 256) & 255;
        sIn[pi][pj] = inC[gi * 256 + gj];
    }
    __syncthreads();

    // ---- taps in registers (g symmetric -> 23 regs) ----
    float tapA[17], tC6[6];
#pragma unroll
    for (int k = 0; k < 17; ++k) tapA[k] = sG[1 + 4 * k];
#pragma unroll
    for (int m = 0; m < 6; ++m) tC6[m] = sG[12 + 4 * m];

    // ---- horizontal polyphase: rows 1..48 x 32 col-quads -> sMid ----
#pragma unroll
    for (int it = 0; it < 6; ++it) {
        const int idx = tid + it * 256;             // 0..1535
        const int c = idx & 31, row = 1 + (idx >> 5);
        float a0 = 0.f, a1 = 0.f, a2 = 0.f, a3 = 0.f;
#pragma unroll
        for (int k = 0; k < 17; ++k) {
            const float w = sIn[row][c + 17 - k];
            a1 += tapA[k] * w;
            a3 += tapA[16 - k] * w;
            if (k >= 3 && k <= 14) {
                const int m = k - 3;
                a0 += tC6[m < 6 ? m : 11 - m] * w;
            }
            if (k == 8) a2 = w;
        }
        float4 v; v.x = a0; v.y = a1; v.z = a2; v.w = a3;
        *(float4*)&sMid[row][4 * c] = v;
    }
    __syncthreads();

    // ---- vertical polyphase: 4 row-groups/thread, rolling 20-row window ----
    const int c = tid & 31, gp = tid >> 5;          // c: col-quad, gp: group-of-4-rowgroups
    float4 A[4][4];                                  // A[i][phase]
#pragma unroll
    for (int i = 0; i < 4; ++i)
#pragma unroll
        for (int p = 0; p < 4; ++p) { A[i][p].x = 0.f; A[i][p].y = 0.f; A[i][p].z = 0.f; A[i][p].w = 0.f; }

#pragma unroll
    for (int d = 1; d <= 20; ++d) {
        const float4 R = *(const float4*)&sMid[4 * gp + d][4 * c];
#pragma unroll
        for (int i = 0; i < 4; ++i) {
            const int k = i + 17 - d;               // tap index for row-group 4*gp+i
            if (k < 0 || k > 16) continue;
            fma4(A[i][1], tapA[k], R);
            fma4(A[i][3], tapA[16 - k], R);
            if (k >= 3 && k <= 14) {
                const int m = k - 3;
                fma4(A[i][0], tC6[m < 6 ? m : 11 - m], R);
            }
            if (k == 8) A[i][2] = R;                // copy phase: g[0]=1 exactly
        }
    }

    float* outC = out + (size_t)ch * 1024 * 1024;
    const int row0 = 128 * tY + 16 * gp, col = 128 * tX + 4 * c;
#pragma unroll
    for (int i = 0; i < 4; ++i)
#pragma unroll
        for (int p = 0; p < 4; ++p)
            *(float4*)&outC[(size_t)(row0 + 4 * i + p) * W4 + col] = A[i][p];
}

extern "C" void kernel_launch(void* const* d_in, const int* in_sizes, int n_in,
                              void* d_out, int out_size, void* d_ws, size_t ws_size,
                              hipStream_t stream) {
    const float* x    = (const float*)d_in[0];   // (32, 256, 256)
    const float* kern = (const float*)d_in[1];   // 23 taps
    float* out  = (float*)d_out;                 // (32, 1024, 1024)
    float* gbuf = (float*)d_ws;                  // 80 floats

    compute_g<<<dim3(1), dim3(80), 0, stream>>>(kern, gbuf);
    dim3 grid(8, 8, 32);                         // 128x128 output tiles
    up4_fused<<<grid, dim3(256), 0, stream>>>(x, gbuf, out);
}